// Round 16
// baseline (91.389 us; speedup 1.0000x reference)
//
#include <hip/hip_runtime.h>

#define G_TOT 2016
#define NGB32 63
#define HSTR 40   // hb row stride in f16 (80B): fragment-contiguous
#define CSTR 33   // cob row stride (f32)

typedef _Float16 f16;
typedef __attribute__((ext_vector_type(2))) _Float16 v2h;
typedef __attribute__((ext_vector_type(8))) _Float16 v8h;
typedef __attribute__((ext_vector_type(4))) float v4f;

__device__ __forceinline__ v2h pkrtz(float a, float b) {
    return __builtin_bit_cast(v2h, __builtin_amdgcn_cvt_pkrtz(a, b));
}

// ---------------------------------------------------------------------------
// Prep: gather Y into 16x16x32-fragment-ordered f16 tables (per 32-g block).
// ---------------------------------------------------------------------------
__global__ void vg_prep(const float* __restrict__ Y, const float* __restrict__ qw,
                        f16* __restrict__ A1buf, f16* __restrict__ B2buf) {
    const int gb = blockIdx.x;
    const int lane = threadIdx.x & 63;
    const int lhi = lane >> 4, llo = lane & 15;
#pragma unroll
    for (int gh = 0; gh < 2; ++gh) {
        const int g = gb * 32 + gh * 16 + llo;
#pragma unroll
        for (int j = 0; j < 8; ++j) {
            const int k = (j < 4) ? (lhi * 4 + j) : (16 + lhi * 4 + (j - 4));
            const float v = (k < 25) ? Y[k * G_TOT + g] : 0.0f;
            A1buf[((gb * 2 + gh) * 64 + lane) * 8 + j] = (f16)v;
        }
    }
#pragma unroll
    for (int t = 0; t < 2; ++t) {
        const int k = t * 16 + llo;
#pragma unroll
        for (int j = 0; j < 8; ++j) {
            const int g = gb * 32 + ((j < 4) ? (lhi * 4 + j) : (16 + lhi * 4 + (j - 4)));
            const float v = (k < 25) ? Y[k * G_TOT + g] * qw[g] : 0.0f;
            B2buf[((gb * 2 + t) * 64 + lane) * 8 + j] = (f16)v;
        }
    }
}

// ---------------------------------------------------------------------------
// Main fused kernel: ONE BLOCK PER n (grid 512, 2 blocks/CU, one batch).
// All 3 parities fused: x-fragments and A1/B2 table loads amortized 3x, and
// each wave carries 3 INDEPENDENT MFMA1->cross->MFMA2 chains per gb — ILP
// feeds the MFMA pipe where single-chain pipelining (R12/R13) failed.
// Waves = (h = c-half, q = g-half) as R14. Per-p CO reduce + MFMA epilogue.
// ---------------------------------------------------------------------------
template <bool USE_WS>
__global__ __launch_bounds__(256, 2)
void vg_main(const float* __restrict__ x1, const float* __restrict__ x2,
             const float* __restrict__ W1s, const float* __restrict__ W2s,
             const float* __restrict__ Wouts, const float* __restrict__ Y,
             const float* __restrict__ qw,
             const f16* __restrict__ A1buf, const f16* __restrict__ B2buf,
             float* __restrict__ out) {
    __shared__ __align__(16) char smem[15360];
    f16* hb = (f16*)smem;        // [2 spin][96][HSTR] f16 (phase 0, reused per p)
    float* cob = (float*)smem;   // [96][CSTR] f32 (reduce/epilogue; aliased)

    const int n = blockIdx.x;
    const int tid = threadIdx.x;
    const int wid = tid >> 6;
    const int h = wid & 1;       // c-half owned (main loop)
    const int q = wid >> 1;      // g-split (main loop)
    const int lane = tid & 63;
    const int lhi = lane >> 4, llo = lane & 15;

    const v4f zero4 = {0.0f, 0.0f, 0.0f, 0.0f};

    // ---- phase 0a: zero hb once (padding slots stay 0 across p)
    for (int i = tid; i < 3840; i += 256) ((float*)smem)[i] = 0.0f;

    // ---- phase 0b per parity (MFMA channel mix, all 4 waves = (s, ct) quarter).
    // x-fragments (af) loaded ONCE, reused for all 3 parities.
    v8h hfr[3][2][3];            // [p][spin][vc] = 72 VGPR, filled per p
    {
        const int s = wid & 1, ct = wid >> 1;
        const float* xs = (s ? x2 : x1) + n * 2400;
        v8h af[5];
#pragma unroll
        for (int vt = 0; vt < 5; ++vt) {
            const int vkb = vt * 16 + llo;
#pragma unroll
            for (int j = 0; j < 8; ++j) {
                const int f = (j < 4) ? (lhi * 4 + j) : (16 + lhi * 4 + (j - 4));
                af[vt][j] = (vkb < 75) ? (f16)xs[f * 75 + vkb] : (f16)0.0f;
            }
        }
        f16* hbs = hb + s * 96 * HSTR;
        const f16* hfb = &hb[llo * HSTR + lhi * 8];
#pragma unroll 1
        for (int p = 0; p < 3; ++p) {
            __syncthreads();     // prev hoist / zero visible before writes
            const float* Wp = (s ? W2s : W1s) + p * 5120;
            v8h bf[5];
#pragma unroll
            for (int l = 0; l < 5; ++l)
#pragma unroll
                for (int j = 0; j < 8; ++j) {
                    const int f = (j < 4) ? (lhi * 4 + j) : (16 + lhi * 4 + (j - 4));
                    bf[l][j] = (f16)Wp[l * 1024 + f * 32 + ct * 16 + llo];
                }
#pragma unroll
            for (int vt = 0; vt < 5; ++vt) {
                v4f D[5];
#pragma unroll
                for (int l = 0; l < 5; ++l)
                    D[l] = __builtin_amdgcn_mfma_f32_16x16x32_f16(af[vt], bf[l], zero4, 0, 0, 0);
#pragma unroll
                for (int j = 0; j < 4; ++j) {
                    const int vk = vt * 16 + lhi * 4 + j;
                    if (vk < 75) {
                        const int v = (vk >= 50) ? 2 : ((vk >= 25) ? 1 : 0);
                        const int k = vk - v * 25;
                        const float val = (k < 1) ? D[0][j]
                                        : (k < 4) ? D[1][j]
                                        : (k < 9) ? D[2][j]
                                        : (k < 16) ? D[3][j]
                                        : D[4][j];
                        const int ks = (k < 16) ? ((k >> 2) * 8 + (k & 3))
                                               : (((k - 16) >> 2) * 8 + 4 + ((k - 16) & 3));
                        hbs[(v * 32 + ct * 16 + llo) * HSTR + ks] = (f16)val;
                    }
                }
            }
            __syncthreads();     // writes visible before hoist
            // hoist this wave's h fragments for parity p: tiles Rn = 2*vc + h
#pragma unroll
            for (int s2 = 0; s2 < 2; ++s2)
#pragma unroll
                for (int vc = 0; vc < 3; ++vc)
                    hfr[p][s2][vc] = *(const v8h*)(hfb + (s2 * 96 + (2 * vc + h) * 16) * HSTR);
        }
    }

    v4f coacc[3][3][2];          // [p][vc][t] = 72 VGPR
#pragma unroll
    for (int p = 0; p < 3; ++p)
#pragma unroll
        for (int vc = 0; vc < 3; ++vc)
#pragma unroll
            for (int t = 0; t < 2; ++t) coacc[p][vc][t] = zero4;

    union A2U { v2h p[4]; v8h v; };

    // packed-f16 cross for one gh-half into a2u slots gh*2+{0,1}
    auto crossh = [&](const v4f (&ag)[2][3], A2U (&a2u)[3], int gh) {
        v2h g1[3][2], g2[3][2];
#pragma unroll
        for (int vc = 0; vc < 3; ++vc) {
            g1[vc][0] = pkrtz(ag[0][vc][0], ag[0][vc][1]);
            g1[vc][1] = pkrtz(ag[0][vc][2], ag[0][vc][3]);
            g2[vc][0] = pkrtz(ag[1][vc][0], ag[1][vc][1]);
            g2[vc][1] = pkrtz(ag[1][vc][2], ag[1][vc][3]);
        }
#pragma unroll
        for (int jp = 0; jp < 2; ++jp) {
            a2u[0].p[gh * 2 + jp] = g1[1][jp] * g2[2][jp] - g1[2][jp] * g2[1][jp];
            a2u[1].p[gh * 2 + jp] = g1[2][jp] * g2[0][jp] - g1[0][jp] * g2[2][jp];
            a2u[2].p[gh * 2 + jp] = g1[0][jp] * g2[1][jp] - g1[1][jp] * g2[0][jp];
        }
    };

    // ---- main loop: wave (h,q) walks gb = q, q+2, ...; 3 parity chains per gb
    if constexpr (USE_WS) {
        const v8h* base_a = (const v8h*)A1buf + lane;
        const v8h* base_b = (const v8h*)B2buf + lane;
        const int iters = (NGB32 - q + 1) >> 1;        // q=0:32, q=1:31
        v8h Aa = base_a[q * 128], Ab = base_a[q * 128 + 64];
        v8h Ba = base_b[q * 128], Bb = base_b[q * 128 + 64];
        for (int it = 0; it < iters; ++it) {
            const int nb = (it + 1 < iters) ? (q + 2 * (it + 1)) * 128 : q * 128;
            v8h An0 = base_a[nb], An1 = base_a[nb + 64];
            v8h Bn0 = base_b[nb], Bn1 = base_b[nb + 64];
#pragma unroll
            for (int p = 0; p < 3; ++p) {
                v4f ag[2][3];
                A2U a2u[3];
#pragma unroll
                for (int s = 0; s < 2; ++s)
#pragma unroll
                    for (int vc = 0; vc < 3; ++vc)
                        ag[s][vc] = __builtin_amdgcn_mfma_f32_16x16x32_f16(
                            Aa, hfr[p][s][vc], zero4, 0, 0, 0);
                crossh(ag, a2u, 0);
#pragma unroll
                for (int s = 0; s < 2; ++s)
#pragma unroll
                    for (int vc = 0; vc < 3; ++vc)
                        ag[s][vc] = __builtin_amdgcn_mfma_f32_16x16x32_f16(
                            Ab, hfr[p][s][vc], zero4, 0, 0, 0);
                crossh(ag, a2u, 1);
#pragma unroll
                for (int vc = 0; vc < 3; ++vc) {
                    coacc[p][vc][0] = __builtin_amdgcn_mfma_f32_16x16x32_f16(a2u[vc].v, Ba, coacc[p][vc][0], 0, 0, 0);
                    coacc[p][vc][1] = __builtin_amdgcn_mfma_f32_16x16x32_f16(a2u[vc].v, Bb, coacc[p][vc][1], 0, 0, 0);
                }
            }
            Aa = An0; Ab = An1; Ba = Bn0; Bb = Bn1;
        }
    } else {
        for (int gb = q; gb < NGB32; gb += 2) {
            v8h Aa, Ab, Ba, Bb;
#pragma unroll
            for (int j = 0; j < 8; ++j) {
                const int gg = gb * 32 + ((j < 4) ? (lhi * 4 + j) : (16 + lhi * 4 + (j - 4)));
                const float qg = qw[gg];
                Ba[j] = (f16)(Y[llo * G_TOT + gg] * qg);
                const int k1 = 16 + llo;
                Bb[j] = (f16)((k1 < 25) ? Y[k1 * G_TOT + gg] * qg : 0.0f);
                const int k = (j < 4) ? (lhi * 4 + j) : (16 + lhi * 4 + (j - 4));
                Aa[j] = (f16)((k < 25) ? Y[k * G_TOT + gb * 32 + llo] : 0.0f);
                Ab[j] = (f16)((k < 25) ? Y[k * G_TOT + gb * 32 + 16 + llo] : 0.0f);
            }
#pragma unroll
            for (int p = 0; p < 3; ++p) {
                v4f ag[2][3];
                A2U a2u[3];
#pragma unroll
                for (int s = 0; s < 2; ++s)
#pragma unroll
                    for (int vc = 0; vc < 3; ++vc)
                        ag[s][vc] = __builtin_amdgcn_mfma_f32_16x16x32_f16(
                            Aa, hfr[p][s][vc], zero4, 0, 0, 0);
                crossh(ag, a2u, 0);
#pragma unroll
                for (int s = 0; s < 2; ++s)
#pragma unroll
                    for (int vc = 0; vc < 3; ++vc)
                        ag[s][vc] = __builtin_amdgcn_mfma_f32_16x16x32_f16(
                            Ab, hfr[p][s][vc], zero4, 0, 0, 0);
                crossh(ag, a2u, 1);
#pragma unroll
                for (int vc = 0; vc < 3; ++vc) {
                    coacc[p][vc][0] = __builtin_amdgcn_mfma_f32_16x16x32_f16(a2u[vc].v, Ba, coacc[p][vc][0], 0, 0, 0);
                    coacc[p][vc][1] = __builtin_amdgcn_mfma_f32_16x16x32_f16(a2u[vc].v, Bb, coacc[p][vc][1], 0, 0, 0);
                }
            }
        }
    }

    // ---- per parity: CO reduce (q-stages) + MFMA epilogue
#pragma unroll 1
    for (int p = 0; p < 3; ++p) {
        __syncthreads();         // prev epilogue reads done / hb alias dead
        if (q == 0) {
#pragma unroll
            for (int vc = 0; vc < 3; ++vc)
#pragma unroll
                for (int t = 0; t < 2; ++t)
#pragma unroll
                    for (int j = 0; j < 4; ++j) {
                        const int row = (2 * vc + h) * 16 + lhi * 4 + j;
                        cob[row * CSTR + t * 16 + llo] = coacc[p][vc][t][j];
                    }
        }
        __syncthreads();
        if (q == 1) {
#pragma unroll
            for (int vc = 0; vc < 3; ++vc)
#pragma unroll
                for (int t = 0; t < 2; ++t)
#pragma unroll
                    for (int j = 0; j < 4; ++j) {
                        const int row = (2 * vc + h) * 16 + lhi * 4 + j;
                        cob[row * CSTR + t * 16 + llo] += coacc[p][vc][t][j];
                    }
        }
        __syncthreads();
        if (wid < 3) {
            const int v = wid;
            const float* Wop = Wouts + p * 5120;
            float* outp = out + (n * 96 + p * 32) * 75 + v * 25;
            const int k0s[5] = {0, 1, 4, 9, 16};
            const int kws[5] = {1, 3, 5, 7, 9};
#pragma unroll
            for (int l = 0; l < 5; ++l) {
                const int k0 = k0s[l], kw = kws[l];
                v8h Bf;
                const int kk = (llo < kw) ? (k0 + llo) : k0;
#pragma unroll
                for (int j = 0; j < 8; ++j) {
                    const int a = (j < 4) ? (lhi * 4 + j) : (16 + lhi * 4 + (j - 4));
                    const float bv = (llo < kw) ? cob[(v * 32 + a) * CSTR + kk] : 0.0f;
                    Bf[j] = (f16)bv;
                }
#pragma unroll
                for (int bt = 0; bt < 2; ++bt) {
                    v8h Af;
#pragma unroll
                    for (int j = 0; j < 8; ++j) {
                        const int a = (j < 4) ? (lhi * 4 + j) : (16 + lhi * 4 + (j - 4));
                        Af[j] = (f16)Wop[l * 1024 + a * 32 + bt * 16 + llo];
                    }
                    v4f D = __builtin_amdgcn_mfma_f32_16x16x32_f16(Af, Bf, zero4, 0, 0, 0);
                    if (llo < kw) {
#pragma unroll
                        for (int jj = 0; jj < 4; ++jj)
                            outp[(bt * 16 + lhi * 4 + jj) * 75 + k0 + llo] = D[jj];
                    }
                }
            }
        }
    }
}

extern "C" void kernel_launch(void* const* d_in, const int* in_sizes, int n_in,
                              void* d_out, int out_size, void* d_ws, size_t ws_size,
                              hipStream_t stream) {
    const float* x1 = (const float*)d_in[0];
    const float* x2 = (const float*)d_in[1];
    const float* W1s = (const float*)d_in[2];
    const float* W2s = (const float*)d_in[3];
    const float* Wouts = (const float*)d_in[4];
    const float* Y = (const float*)d_in[5];
    const float* qw = (const float*)d_in[6];
    float* out = (float*)d_out;

    f16* A1buf = (f16*)d_ws;
    f16* B2buf = (f16*)((char*)d_ws + 129024);

    if (ws_size >= 258048) {
        vg_prep<<<NGB32, 64, 0, stream>>>(Y, qw, A1buf, B2buf);
        vg_main<true><<<512, 256, 0, stream>>>(x1, x2, W1s, W2s, Wouts, Y, qw,
                                               A1buf, B2buf, out);
    } else {
        vg_main<false><<<512, 256, 0, stream>>>(x1, x2, W1s, W2s, Wouts, Y, qw,
                                                nullptr, nullptr, out);
    }
}

// Round 17
// 73.195 us; speedup vs baseline: 1.2486x; 1.2486x over previous
//
#include <hip/hip_runtime.h>

#define G_TOT 2016
#define NGB32 63
#define HSTR 40   // hb row stride in f16 (80B): fragment-contiguous
#define CSTR 33   // cob row stride (f32)

typedef _Float16 f16;
typedef __attribute__((ext_vector_type(2))) _Float16 v2h;
typedef __attribute__((ext_vector_type(8))) _Float16 v8h;
typedef __attribute__((ext_vector_type(4))) float v4f;

__device__ __forceinline__ v2h pkrtz(float a, float b) {
    return __builtin_bit_cast(v2h, __builtin_amdgcn_cvt_pkrtz(a, b));
}

// ---------------------------------------------------------------------------
// Prep: gather Y into 16x16x32-fragment-ordered f16 tables (per 32-g block).
// ---------------------------------------------------------------------------
__global__ void vg_prep(const float* __restrict__ Y, const float* __restrict__ qw,
                        f16* __restrict__ A1buf, f16* __restrict__ B2buf) {
    const int gb = blockIdx.x;
    const int lane = threadIdx.x & 63;
    const int lhi = lane >> 4, llo = lane & 15;
#pragma unroll
    for (int gh = 0; gh < 2; ++gh) {
        const int g = gb * 32 + gh * 16 + llo;
#pragma unroll
        for (int j = 0; j < 8; ++j) {
            const int k = (j < 4) ? (lhi * 4 + j) : (16 + lhi * 4 + (j - 4));
            const float v = (k < 25) ? Y[k * G_TOT + g] : 0.0f;
            A1buf[((gb * 2 + gh) * 64 + lane) * 8 + j] = (f16)v;
        }
    }
#pragma unroll
    for (int t = 0; t < 2; ++t) {
        const int k = t * 16 + llo;
#pragma unroll
        for (int j = 0; j < 8; ++j) {
            const int g = gb * 32 + ((j < 4) ? (lhi * 4 + j) : (16 + lhi * 4 + (j - 4)));
            const float v = (k < 25) ? Y[k * G_TOT + g] * qw[g] : 0.0f;
            B2buf[((gb * 2 + t) * 64 + lane) * 8 + j] = (f16)v;
        }
    }
}

// ---------------------------------------------------------------------------
// Main fused kernel: 256 threads per (n, parity); waves = (h = c-half, q = g-half).
// R14 structure, register-trimmed for 4 waves/SIMD: NO prefetch ping-pong
// (TLP from doubled occupancy hides the L2 frag-load latency instead of ILP),
// plain per-gh body (no sched_barrier schedule). __launch_bounds__(256,4).
// Phase 0b: MFMA channel mix on all 4 waves. Epilogue: MFMA (R14).
// ---------------------------------------------------------------------------
template <bool USE_WS>
__global__ __launch_bounds__(256, 4)
void vg_main(const float* __restrict__ x1, const float* __restrict__ x2,
             const float* __restrict__ W1s, const float* __restrict__ W2s,
             const float* __restrict__ Wouts, const float* __restrict__ Y,
             const float* __restrict__ qw,
             const f16* __restrict__ A1buf, const f16* __restrict__ B2buf,
             float* __restrict__ out) {
    __shared__ __align__(16) char smem[15360];
    f16* hb = (f16*)smem;        // [2 spin][96][HSTR] f16 (phase 0)
    float* cob = (float*)smem;   // [96][CSTR] f32 (reduce/epilogue; aliased)

    const int bid = blockIdx.x;
    const int n = bid / 3, p = bid % 3;
    const int tid = threadIdx.x;
    const int wid = tid >> 6;
    const int h = wid & 1;       // c-half owned (main loop)
    const int q = wid >> 1;      // g-split (main loop)
    const int lane = tid & 63;
    const int lhi = lane >> 4, llo = lane & 15;

    const v4f zero4 = {0.0f, 0.0f, 0.0f, 0.0f};

    // ---- phase 0a: zero hb (padding slots must be 0)
    for (int i = tid; i < 3840; i += 256) ((float*)smem)[i] = 0.0f;
    __syncthreads();

    // ---- phase 0b (MFMA, all 4 waves): wave (s, ct) computes its quarter.
    {
        const int s = wid & 1, ct = wid >> 1;
        const float* xs = (s ? x2 : x1) + n * 2400;
        const float* Wp = (s ? W2s : W1s) + p * 5120;
        v8h bf[5];
#pragma unroll
        for (int l = 0; l < 5; ++l)
#pragma unroll
            for (int j = 0; j < 8; ++j) {
                const int f = (j < 4) ? (lhi * 4 + j) : (16 + lhi * 4 + (j - 4));
                bf[l][j] = (f16)Wp[l * 1024 + f * 32 + ct * 16 + llo];
            }
        f16* hbs = hb + s * 96 * HSTR;
#pragma unroll
        for (int vt = 0; vt < 5; ++vt) {
            v8h af;
            const int vkb = vt * 16 + llo;
#pragma unroll
            for (int j = 0; j < 8; ++j) {
                const int f = (j < 4) ? (lhi * 4 + j) : (16 + lhi * 4 + (j - 4));
                af[j] = (vkb < 75) ? (f16)xs[f * 75 + vkb] : (f16)0.0f;
            }
            v4f D[5];
#pragma unroll
            for (int l = 0; l < 5; ++l)
                D[l] = __builtin_amdgcn_mfma_f32_16x16x32_f16(af, bf[l], zero4, 0, 0, 0);
#pragma unroll
            for (int j = 0; j < 4; ++j) {
                const int vk = vt * 16 + lhi * 4 + j;
                if (vk < 75) {
                    const int v = (vk >= 50) ? 2 : ((vk >= 25) ? 1 : 0);
                    const int k = vk - v * 25;
                    const float val = (k < 1) ? D[0][j]
                                    : (k < 4) ? D[1][j]
                                    : (k < 9) ? D[2][j]
                                    : (k < 16) ? D[3][j]
                                    : D[4][j];
                    const int ks = (k < 16) ? ((k >> 2) * 8 + (k & 3))
                                           : (((k - 16) >> 2) * 8 + 4 + ((k - 16) & 3));
                    hbs[(v * 32 + ct * 16 + llo) * HSTR + ks] = (f16)val;
                }
            }
        }
    }
    __syncthreads();

    // ---- hoist this wave's h fragments: tiles Rn = 2*vc + h (6 x v8h = 24 VGPR)
    v8h hfr[2][3];
    {
        const f16* hfb = &hb[llo * HSTR + lhi * 8];
#pragma unroll
        for (int s = 0; s < 2; ++s)
#pragma unroll
            for (int vc = 0; vc < 3; ++vc)
                hfr[s][vc] = *(const v8h*)(hfb + (s * 96 + (2 * vc + h) * 16) * HSTR);
    }

    v4f coacc[3][2];
#pragma unroll
    for (int vc = 0; vc < 3; ++vc)
#pragma unroll
        for (int t = 0; t < 2; ++t) coacc[vc][t] = zero4;

    union A2U { v2h p[4]; v8h v; };

    // one gh-half MFMA1 cluster: 6 MFMAs into ag[2][3] (24 regs)
    auto mfma1h = [&](const v8h& a1, v4f (&ag)[2][3]) {
#pragma unroll
        for (int s = 0; s < 2; ++s)
#pragma unroll
            for (int vc = 0; vc < 3; ++vc)
                ag[s][vc] = __builtin_amdgcn_mfma_f32_16x16x32_f16(
                    a1, hfr[s][vc], zero4, 0, 0, 0);
    };

    // packed-f16 cross for one gh-half into a2u slots gh*2+{0,1}
    auto crossh = [&](const v4f (&ag)[2][3], A2U (&a2u)[3], int gh) {
        v2h g1[3][2], g2[3][2];
#pragma unroll
        for (int vc = 0; vc < 3; ++vc) {
            g1[vc][0] = pkrtz(ag[0][vc][0], ag[0][vc][1]);
            g1[vc][1] = pkrtz(ag[0][vc][2], ag[0][vc][3]);
            g2[vc][0] = pkrtz(ag[1][vc][0], ag[1][vc][1]);
            g2[vc][1] = pkrtz(ag[1][vc][2], ag[1][vc][3]);
        }
#pragma unroll
        for (int jp = 0; jp < 2; ++jp) {
            a2u[0].p[gh * 2 + jp] = g1[1][jp] * g2[2][jp] - g1[2][jp] * g2[1][jp];
            a2u[1].p[gh * 2 + jp] = g1[2][jp] * g2[0][jp] - g1[0][jp] * g2[2][jp];
            a2u[2].p[gh * 2 + jp] = g1[0][jp] * g2[1][jp] - g1[1][jp] * g2[0][jp];
        }
    };

    auto mfma2 = [&](A2U (&a2u)[3], const v8h& b2lo, const v8h& b2hi) {
#pragma unroll
        for (int vc = 0; vc < 3; ++vc) {
            coacc[vc][0] = __builtin_amdgcn_mfma_f32_16x16x32_f16(a2u[vc].v, b2lo, coacc[vc][0], 0, 0, 0);
            coacc[vc][1] = __builtin_amdgcn_mfma_f32_16x16x32_f16(a2u[vc].v, b2hi, coacc[vc][1], 0, 0, 0);
        }
    };

    // ---- main loop: wave (h,q) walks gb = q, q+2, ... — simple body, TLP
    // (4 waves/SIMD) hides the L2 frag-load latency.
    if constexpr (USE_WS) {
        const v8h* base_a = (const v8h*)A1buf + lane;
        const v8h* base_b = (const v8h*)B2buf + lane;
        for (int gb = q; gb < NGB32; gb += 2) {
            const int off = gb * 128;
            const v8h Aa = base_a[off], Ab = base_a[off + 64];
            const v8h Ba = base_b[off], Bb = base_b[off + 64];
            A2U a2u[3];
            v4f ag[2][3];
            mfma1h(Aa, ag);
            crossh(ag, a2u, 0);
            mfma1h(Ab, ag);
            crossh(ag, a2u, 1);
            mfma2(a2u, Ba, Bb);
        }
    } else {
        for (int gb = q; gb < NGB32; gb += 2) {
            v8h Aa, Ab, Ba, Bb;
#pragma unroll
            for (int j = 0; j < 8; ++j) {
                const int gg = gb * 32 + ((j < 4) ? (lhi * 4 + j) : (16 + lhi * 4 + (j - 4)));
                const float qg = qw[gg];
                Ba[j] = (f16)(Y[llo * G_TOT + gg] * qg);
                const int k1 = 16 + llo;
                Bb[j] = (f16)((k1 < 25) ? Y[k1 * G_TOT + gg] * qg : 0.0f);
                const int k = (j < 4) ? (lhi * 4 + j) : (16 + lhi * 4 + (j - 4));
                Aa[j] = (f16)((k < 25) ? Y[k * G_TOT + gb * 32 + llo] : 0.0f);
                Ab[j] = (f16)((k < 25) ? Y[k * G_TOT + gb * 32 + 16 + llo] : 0.0f);
            }
            A2U a2u[3];
            v4f ag[2][3];
            mfma1h(Aa, ag);
            crossh(ag, a2u, 0);
            mfma1h(Ab, ag);
            crossh(ag, a2u, 1);
            mfma2(a2u, Ba, Bb);
        }
    }

    // ---- CO: q=0 writes, q=1 accumulates (waves own disjoint rows across h)
    __syncthreads();
    if (q == 0) {
#pragma unroll
        for (int vc = 0; vc < 3; ++vc)
#pragma unroll
            for (int t = 0; t < 2; ++t)
#pragma unroll
                for (int j = 0; j < 4; ++j) {
                    const int row = (2 * vc + h) * 16 + lhi * 4 + j;
                    cob[row * CSTR + t * 16 + llo] = coacc[vc][t][j];
                }
    }
    __syncthreads();
    if (q == 1) {
#pragma unroll
        for (int vc = 0; vc < 3; ++vc)
#pragma unroll
            for (int t = 0; t < 2; ++t)
#pragma unroll
                for (int j = 0; j < 4; ++j) {
                    const int row = (2 * vc + h) * 16 + lhi * 4 + j;
                    cob[row * CSTR + t * 16 + llo] += coacc[vc][t][j];
                }
    }
    __syncthreads();

    // ---- epilogue (MFMA): wave v=wid<3: out = W_l^T x co
    if (wid < 3) {
        const int v = wid;
        const float* Wop = Wouts + p * 5120;
        float* outp = out + (n * 96 + p * 32) * 75 + v * 25;
        const int k0s[5] = {0, 1, 4, 9, 16};
        const int kws[5] = {1, 3, 5, 7, 9};
#pragma unroll
        for (int l = 0; l < 5; ++l) {
            const int k0 = k0s[l], kw = kws[l];
            v8h Bf;
            const int kk = (llo < kw) ? (k0 + llo) : k0;
#pragma unroll
            for (int j = 0; j < 8; ++j) {
                const int a = (j < 4) ? (lhi * 4 + j) : (16 + lhi * 4 + (j - 4));
                const float bv = (llo < kw) ? cob[(v * 32 + a) * CSTR + kk] : 0.0f;
                Bf[j] = (f16)bv;
            }
#pragma unroll
            for (int bt = 0; bt < 2; ++bt) {
                v8h Af;
#pragma unroll
                for (int j = 0; j < 8; ++j) {
                    const int a = (j < 4) ? (lhi * 4 + j) : (16 + lhi * 4 + (j - 4));
                    Af[j] = (f16)Wop[l * 1024 + a * 32 + bt * 16 + llo];
                }
                v4f D = __builtin_amdgcn_mfma_f32_16x16x32_f16(Af, Bf, zero4, 0, 0, 0);
                if (llo < kw) {
#pragma unroll
                    for (int jj = 0; jj < 4; ++jj)
                        outp[(bt * 16 + lhi * 4 + jj) * 75 + k0 + llo] = D[jj];
                }
            }
        }
    }
}

extern "C" void kernel_launch(void* const* d_in, const int* in_sizes, int n_in,
                              void* d_out, int out_size, void* d_ws, size_t ws_size,
                              hipStream_t stream) {
    const float* x1 = (const float*)d_in[0];
    const float* x2 = (const float*)d_in[1];
    const float* W1s = (const float*)d_in[2];
    const float* W2s = (const float*)d_in[3];
    const float* Wouts = (const float*)d_in[4];
    const float* Y = (const float*)d_in[5];
    const float* qw = (const float*)d_in[6];
    float* out = (float*)d_out;

    f16* A1buf = (f16*)d_ws;
    f16* B2buf = (f16*)((char*)d_ws + 129024);

    if (ws_size >= 258048) {
        vg_prep<<<NGB32, 64, 0, stream>>>(Y, qw, A1buf, B2buf);
        vg_main<true><<<1536, 256, 0, stream>>>(x1, x2, W1s, W2s, Wouts, Y, qw,
                                                A1buf, B2buf, out);
    } else {
        vg_main<false><<<1536, 256, 0, stream>>>(x1, x2, W1s, W2s, Wouts, Y, qw,
                                                 nullptr, nullptr, out);
    }
}